// Round 6
// baseline (4114.228 us; speedup 1.0000x reference)
//
#include <hip/hip_runtime.h>
#include <hip/hip_bf16.h>
#include <hip/hip_fp16.h>

// APPNP: h0 = MLP(x); 10x { h = 0.9 * A_hat h + 0.1 * h0 }; log_softmax.
// A_hat = D^-1/2 (A + I) D^-1/2 over col-targets (PyG gcn_norm).
//
// R9 post-mortem: edge-parallel gather landed at 365us/iter with hbm=109GB/s,
// VALU=1% -> pure latency starvation: one dependent {edge->row->atomics}
// chain per wave = ~100KB in flight chip-wide = 111GB/s predicted (matches).
// R10: (a) 4-deep software pipeline (4 edges+rows in flight per lane);
// (b) 128-node buckets -> NB=782 blocks x 256 thr -> ~3 blocks/CU on ALL
// 256 CUs (was 196 blocks on 196 CUs); (c) nt hints on epk2/h10/hnext so
// the 3.2MB hcur row table stays L2-resident. LDS float atomics proven
// fine (no CAS spin: VALU 1%).

typedef unsigned short u16;
typedef __attribute__((ext_vector_type(8))) short short8;
typedef __attribute__((ext_vector_type(4))) float f32x4;
typedef __attribute__((ext_vector_type(4))) unsigned u32x4;
typedef __attribute__((ext_vector_type(2))) unsigned u32x2;

#define WPB 4        // waves per 256-thread block (mlp/out)
#define BSH 7        // 128 nodes per bucket
#define BN 128
#define NBMAX 800
#define CAP 4864     // slots per bucket region (mean 4092, +12 sigma)
#define SCWG 392     // scatter WGs (chunk ~8.2k edges)

// ---- helpers -------------------------------------------------------------
__device__ __forceinline__ float loadF(const void* p, size_t i, int bf) {
  if (bf) return __bfloat162float(((const __hip_bfloat16*)p)[i]);
  return ((const float*)p)[i];
}
__device__ __forceinline__ float blo(unsigned u) {
  return __uint_as_float(u << 16);
}
__device__ __forceinline__ float bhi(unsigned u) {
  return __uint_as_float(u & 0xffff0000u);
}
__device__ __forceinline__ u16 f2b(float v) {
  __hip_bfloat16 b = __float2bfloat16(v);
  return *reinterpret_cast<u16*>(&b);
}
__device__ __forceinline__ unsigned pk2(float lo, float hi) {
  return (unsigned)f2b(lo) | ((unsigned)f2b(hi) << 16);
}
__device__ __forceinline__ int clampV(int v, int hi) {
  v = v < 0 ? 0 : v;
  return v >= hi ? hi - 1 : v;
}

// flags[0]: 1 if float tensors bf16; flags[1]: 1 if edge_index int64.
__global__ void detect_k(const void* x, const int* ei, int* flags) {
  __shared__ int red[2];
  const int tid = threadIdx.x;              // 1024 threads
  if (tid < 2) red[tid] = 0;
  __syncthreads();
  const __hip_bfloat16* xb = (const __hip_bfloat16*)x;
  float v = __bfloat162float(xb[tid]);
  int sane = (v == v && fabsf(v) < 64.f) ? 1 : 0;
  int zer = (ei[2 * tid + 1] == 0) ? 1 : 0;
  atomicAdd(&red[0], sane);
  atomicAdd(&red[1], zer);
  __syncthreads();
  if (tid == 0) {
    flags[0] = (red[0] >= 1024 - 32) ? 1 : 0;
    flags[1] = (red[1] >= 1024 - 128) ? 1 : 0;
  }
}

// Two-pass chunked scatter: per WG, (A) LDS-histogram chunk over buckets,
// (B) reserve one contiguous range per bucket, (C) re-read chunk and write
// (src,dst) into the WG-owned run -> full-line writes from one CU.
// Arrival order within a bucket stays random -> good LDS-atomic spread.
__global__ __launch_bounds__(256) void scat_k(
    const int* __restrict__ ei, int E, int N, int NB,
    int* __restrict__ gcur, uint2* __restrict__ bpair,
    const int* __restrict__ flags) {
  __shared__ int hist[NBMAX];
  __shared__ int resv[NBMAX];
  const int tid = threadIdx.x;
  const int chunk = (E + SCWG - 1) / SCWG;
  const int e0 = blockIdx.x * chunk;
  const int e1 = min(e0 + chunk, E);
  if (e0 >= E) return;
  const int wide = flags[1];
  for (int i = tid; i < NB; i += 256) hist[i] = 0;
  __syncthreads();
  for (int e = e0 + tid; e < e1; e += 256) {
    int c = wide ? ei[2 * ((long)E + e)] : ei[(long)E + e];
    atomicAdd(&hist[clampV(c, N) >> BSH], 1);
  }
  __syncthreads();
  for (int b = tid; b < NB; b += 256) {
    int cnt = hist[b];
    resv[b] = cnt ? atomicAdd(&gcur[b], cnt) : 0;
  }
  __syncthreads();
  for (int i = tid; i < NB; i += 256) hist[i] = 0;
  __syncthreads();
  for (int e = e0 + tid; e < e1; e += 256) {
    int r = wide ? ei[2 * (long)e] : ei[e];
    int c = wide ? ei[2 * ((long)E + e)] : ei[(long)E + e];
    r = clampV(r, N); c = clampV(c, N);
    const int b = c >> BSH;
    const int pos = resv[b] + atomicAdd(&hist[b], 1);
    if (pos < CAP)
      bpair[(size_t)b * CAP + pos] = make_uint2((unsigned)r, (unsigned)c);
  }
}

// Tiny serial scan over bucket totals -> compact edge-stream bases.
__global__ void bscan_k(const int* __restrict__ gcur, int NB,
                        int* __restrict__ cbase) {
  if (threadIdx.x == 0) {
    int s = 0;
    for (int b = 0; b < NB; b++) {
      cbase[b] = s;
      s += min(gcur[b], CAP);
    }
    cbase[NB] = s;
  }
}

// Per bucket: LDS histogram over its 128 nodes -> dinv only.
__global__ __launch_bounds__(256) void deg_k(
    const uint2* __restrict__ bpair, const int* __restrict__ gcur,
    float* __restrict__ dinv, int N, int NB) {
  __shared__ int lhist[BN];
  const int b = blockIdx.x;
  const int tid = threadIdx.x;
  const int nb0 = b << BSH;
  const int nn = min(BN, N - nb0);
  if (tid < BN) lhist[tid] = 0;
  __syncthreads();
  const size_t wbeg = (size_t)b * CAP;
  const int cnt = min(gcur[b], CAP);
  for (int i = tid; i < cnt; i += 256)
    atomicAdd(&lhist[clampV((int)bpair[wbeg + i].y - nb0, BN)], 1);
  __syncthreads();
  if (tid < nn) dinv[nb0 + tid] = rsqrtf(1.0f + (float)lhist[tid]);
}

// Per bucket: compact packed edges {src, dstLocal<<16 | fp16(norm)}.
// norm = dinv[src]*dinv[dst] in (0,1] -> fp16 (rel err 5e-4), sign 0.
__global__ __launch_bounds__(256) void pack_k(
    const uint2* __restrict__ bpair, const int* __restrict__ gcur,
    const int* __restrict__ cbase, const float* __restrict__ dinv,
    uint2* __restrict__ epk2, int N, int NB) {
  __shared__ float ldv[BN];
  const int b = blockIdx.x;
  const int tid = threadIdx.x;
  const int nb0 = b << BSH;
  const int nn = min(BN, N - nb0);
  if (tid < nn) ldv[tid] = dinv[nb0 + tid];
  __syncthreads();
  const size_t wbeg = (size_t)b * CAP;
  const int cnt = min(gcur[b], CAP);
  const int obase = cbase[b];
  for (int i = tid; i < cnt; i += 256) {
    const uint2 p = bpair[wbeg + i];
    const int dl = clampV((int)p.y - nb0, BN);
    const float nrm = dinv[p.x] * ldv[dl];
    const unsigned h16 = (unsigned)__half_as_ushort(__float2half(nrm));
    epk2[obase + i] = make_uint2(p.x, ((unsigned)dl << 16) | h16);
  }
}

// MLP stage 1 only: H1 = relu(x@W1 + b1), [N,16] bf16 rows, written to
// h10 (the 0.1*H1 source) and pha (iteration ping buffer); s init = 1.0f.
__global__ __launch_bounds__(256) void mlp_k(
    const void* __restrict__ x, const void* __restrict__ W1,
    const void* __restrict__ b1, const int* __restrict__ flags,
    u16* __restrict__ h10, u16* __restrict__ pha, float* __restrict__ sa,
    int N) {
  __shared__ __align__(16) short Blds[8192];   // [kstep][lane][j] bf16
  __shared__ float b1s[16];
  __shared__ float h1s[WPB][16][17];

  const int tid = threadIdx.x;
  const int f0 = flags[0];

  for (int idx = tid; idx < 8192; idx += 256) {
    int ks = idx >> 9, ln = (idx >> 3) & 63, j = idx & 7;
    int k = ks * 32 + ((ln >> 4) << 3) + j;
    int n = ln & 15;
    float w = loadF(W1, (size_t)k * 16 + n, f0);
    Blds[idx] = (short)f2b(w);
  }
  if (tid < 16) b1s[tid] = loadF(b1, tid, f0);
  __syncthreads();

  const int lane = tid & 63;
  const int wv = tid >> 6;
  const int tile = (blockIdx.x * WPB + wv) * 16;
  if (tile >= N) return;

  const int m = lane & 15;
  const int quad = lane >> 4;
  const int row = min(tile + m, N - 1);
  const size_t rowbase = (size_t)row * 512 + (quad << 3);

  f32x4 acc = {0.f, 0.f, 0.f, 0.f};
  if (f0) {
    short8 af[16];
#pragma unroll
    for (int ks = 0; ks < 16; ks++)
      af[ks] = *reinterpret_cast<const short8*>((const u16*)x + rowbase + ks * 32);
#pragma unroll
    for (int ks = 0; ks < 16; ks++) {
      const short8 bf = *reinterpret_cast<const short8*>(&Blds[(ks * 64 + lane) * 8]);
      acc = __builtin_amdgcn_mfma_f32_16x16x32_bf16(af[ks], bf, acc, 0, 0, 0);
    }
  } else {
#pragma unroll
    for (int ks = 0; ks < 16; ks++) {
      short8 a;
      const float* xf = (const float*)x + rowbase + ks * 32;
      const float4 lo = *reinterpret_cast<const float4*>(xf);
      const float4 hi = *reinterpret_cast<const float4*>(xf + 4);
      a[0] = (short)f2b(lo.x); a[1] = (short)f2b(lo.y);
      a[2] = (short)f2b(lo.z); a[3] = (short)f2b(lo.w);
      a[4] = (short)f2b(hi.x); a[5] = (short)f2b(hi.y);
      a[6] = (short)f2b(hi.z); a[7] = (short)f2b(hi.w);
      const short8 bf = *reinterpret_cast<const short8*>(&Blds[(ks * 64 + lane) * 8]);
      acc = __builtin_amdgcn_mfma_f32_16x16x32_bf16(a, bf, acc, 0, 0, 0);
    }
  }

#pragma unroll
  for (int r = 0; r < 4; r++)
    h1s[wv][quad * 4 + r][m] = fmaxf(acc[r] + b1s[m], 0.f);
  // same-wave LDS write->read; compiler inserts lgkmcnt wait, no barrier.

  const int node = lane >> 2;                 // 0..15
  const int gnode = tile + node;
  if (gnode < N) {
    const int cp = (lane & 3) << 2;           // channel offset 0,4,8,12
    uint2 pv;
    pv.x = pk2(h1s[wv][node][cp + 0], h1s[wv][node][cp + 1]);
    pv.y = pk2(h1s[wv][node][cp + 2], h1s[wv][node][cp + 3]);
    *reinterpret_cast<uint2*>(h10 + (((size_t)gnode) << 4) + cp) = pv;
    *reinterpret_cast<uint2*>(pha + (((size_t)gnode) << 4) + cp) = pv;
    if ((lane & 3) == 0) sa[gnode] = 1.0f;
  }
}

#define EDGE_ATOMICS(pp, ra, rb, sv)                                          \
  {                                                                           \
    const int dl_ = (int)((pp).y >> 16);                                      \
    const float n_ =                                                          \
        __half2float(__ushort_as_half((unsigned short)((pp).y & 0xffffu)));   \
    float* ap_ = acc[dl_];                                                    \
    atomicAdd(&ap_[0],  n_ * blo((ra)[0]));                                   \
    atomicAdd(&ap_[1],  n_ * bhi((ra)[0]));                                   \
    atomicAdd(&ap_[2],  n_ * blo((ra)[1]));                                   \
    atomicAdd(&ap_[3],  n_ * bhi((ra)[1]));                                   \
    atomicAdd(&ap_[4],  n_ * blo((ra)[2]));                                   \
    atomicAdd(&ap_[5],  n_ * bhi((ra)[2]));                                   \
    atomicAdd(&ap_[6],  n_ * blo((ra)[3]));                                   \
    atomicAdd(&ap_[7],  n_ * bhi((ra)[3]));                                   \
    atomicAdd(&ap_[8],  n_ * blo((rb)[0]));                                   \
    atomicAdd(&ap_[9],  n_ * bhi((rb)[0]));                                   \
    atomicAdd(&ap_[10], n_ * blo((rb)[1]));                                   \
    atomicAdd(&ap_[11], n_ * bhi((rb)[1]));                                   \
    atomicAdd(&ap_[12], n_ * blo((rb)[2]));                                   \
    atomicAdd(&ap_[13], n_ * bhi((rb)[2]));                                   \
    atomicAdd(&ap_[14], n_ * blo((rb)[3]));                                   \
    atomicAdd(&ap_[15], n_ * bhi((rb)[3]));                                   \
    atomicAdd(&sacc[dl_], n_ * (sv));                                         \
  }

// Edge-parallel gather, 4-deep pipelined. One 256-thr block per 128-node
// bucket (NB=782 -> ~3 blocks/CU chip-wide). Per lane: 4 edges' {8B packed
// edge (nt), 32B row, 4B s} issued together, then 4x17 LDS float adds.
__global__ __launch_bounds__(256) void gatherB_k(
    const u16* __restrict__ hcur, const float* __restrict__ scur,
    const u16* __restrict__ h10, const uint2* __restrict__ epk2,
    const int* __restrict__ cbase, const int* __restrict__ gcur,
    const float* __restrict__ dinv, u16* __restrict__ hnext,
    float* __restrict__ snext, int N, int NB) {
  __shared__ float acc[BN][17];
  __shared__ float sacc[BN];
  const int b = blockIdx.x;
  const int tid = threadIdx.x;
  const int nb0 = b << BSH;
  for (int i = tid; i < BN * 17; i += 256) (&acc[0][0])[i] = 0.f;
  if (tid < BN) sacc[tid] = 0.f;
  __syncthreads();

  const int cnt = min(gcur[b], CAP);
  const int e0 = cbase[b];
  const u32x2* __restrict__ ep = reinterpret_cast<const u32x2*>(epk2 + e0);

  int i = tid;
  for (; i + 768 < cnt; i += 1024) {
    const u32x2 q0 = __builtin_nontemporal_load(ep + i);
    const u32x2 q1 = __builtin_nontemporal_load(ep + i + 256);
    const u32x2 q2 = __builtin_nontemporal_load(ep + i + 512);
    const u32x2 q3 = __builtin_nontemporal_load(ep + i + 768);
    const uint2 p0 = make_uint2(q0[0], q0[1]);
    const uint2 p1 = make_uint2(q1[0], q1[1]);
    const uint2 p2 = make_uint2(q2[0], q2[1]);
    const uint2 p3 = make_uint2(q3[0], q3[1]);
    const u16* r0 = hcur + ((size_t)p0.x << 4);
    const u16* r1 = hcur + ((size_t)p1.x << 4);
    const u16* r2 = hcur + ((size_t)p2.x << 4);
    const u16* r3 = hcur + ((size_t)p3.x << 4);
    const u32x4 a0 = *reinterpret_cast<const u32x4*>(r0);
    const u32x4 b0 = *reinterpret_cast<const u32x4*>(r0 + 8);
    const u32x4 a1 = *reinterpret_cast<const u32x4*>(r1);
    const u32x4 b1 = *reinterpret_cast<const u32x4*>(r1 + 8);
    const u32x4 a2 = *reinterpret_cast<const u32x4*>(r2);
    const u32x4 b2 = *reinterpret_cast<const u32x4*>(r2 + 8);
    const u32x4 a3 = *reinterpret_cast<const u32x4*>(r3);
    const u32x4 b3 = *reinterpret_cast<const u32x4*>(r3 + 8);
    const float s0 = scur[p0.x];
    const float s1 = scur[p1.x];
    const float s2 = scur[p2.x];
    const float s3 = scur[p3.x];
    EDGE_ATOMICS(p0, a0, b0, s0);
    EDGE_ATOMICS(p1, a1, b1, s1);
    EDGE_ATOMICS(p2, a2, b2, s2);
    EDGE_ATOMICS(p3, a3, b3, s3);
  }
  for (; i < cnt; i += 256) {
    const u32x2 q0 = __builtin_nontemporal_load(ep + i);
    const uint2 p0 = make_uint2(q0[0], q0[1]);
    const u16* r0 = hcur + ((size_t)p0.x << 4);
    const u32x4 a0 = *reinterpret_cast<const u32x4*>(r0);
    const u32x4 b0 = *reinterpret_cast<const u32x4*>(r0 + 8);
    const float s0 = scur[p0.x];
    EDGE_ATOMICS(p0, a0, b0, s0);
  }
  __syncthreads();

  // epilogue: 2 threads per target (8 channels each)
  const int tgt = tid >> 1;
  const int ho = (tid & 1) << 3;
  const int node = nb0 + tgt;
  if (tgt < BN && node < N) {
    const float di = dinv[node];
    const float dd = di * di;
    const size_t base = (((size_t)node) << 4) + ho;
    const u32x4 hs = *reinterpret_cast<const u32x4*>(hcur + base);
    const u32x4 hz =
        __builtin_nontemporal_load(reinterpret_cast<const u32x4*>(h10 + base));
    const float* ap = acc[tgt] + ho;
    const float r0 = 0.9f * (ap[0] + dd * blo(hs[0])) + 0.1f * blo(hz[0]);
    const float r1 = 0.9f * (ap[1] + dd * bhi(hs[0])) + 0.1f * bhi(hz[0]);
    const float r2 = 0.9f * (ap[2] + dd * blo(hs[1])) + 0.1f * blo(hz[1]);
    const float r3 = 0.9f * (ap[3] + dd * bhi(hs[1])) + 0.1f * bhi(hz[1]);
    const float r4 = 0.9f * (ap[4] + dd * blo(hs[2])) + 0.1f * blo(hz[2]);
    const float r5 = 0.9f * (ap[5] + dd * bhi(hs[2])) + 0.1f * bhi(hz[2]);
    const float r6 = 0.9f * (ap[6] + dd * blo(hs[3])) + 0.1f * blo(hz[3]);
    const float r7 = 0.9f * (ap[7] + dd * bhi(hs[3])) + 0.1f * bhi(hz[3]);
    u32x4 pv;
    pv[0] = pk2(r0, r1); pv[1] = pk2(r2, r3);
    pv[2] = pk2(r4, r5); pv[3] = pk2(r6, r7);
    __builtin_nontemporal_store(pv, reinterpret_cast<u32x4*>(hnext + base));
    if (ho == 0) snext[node] = 0.9f * (sacc[tgt] + dd * scur[node]) + 0.1f;
  }
}

// Final: out = log_softmax(ph1 @ W2 + s * b2), one wave per node, f32 math.
__global__ __launch_bounds__(256) void out_k(
    const u16* __restrict__ ph1, const float* __restrict__ s,
    const void* __restrict__ W2, const void* __restrict__ b2,
    void* __restrict__ out, const int* __restrict__ flags, int N) {
  __shared__ float W2s[16 * 64];
  __shared__ float b2s[64];
  const int tid = threadIdx.x;
  const int f0 = flags[0];
  for (int i = tid; i < 1024; i += 256) W2s[i] = loadF(W2, i, f0);
  if (tid < 64) b2s[tid] = loadF(b2, tid, f0);
  __syncthreads();
  const int gw = (int)((blockIdx.x * 256u + tid) >> 6);
  if (gw >= N) return;
  const int lane = tid & 63;
  const u16* row = ph1 + (((size_t)gw) << 4);
  const u32x4 ua = *reinterpret_cast<const u32x4*>(row);       // ch 0..7
  const u32x4 ub = *reinterpret_cast<const u32x4*>(row + 8);   // ch 8..15
  float h[16];
  h[0] = blo(ua[0]);  h[1] = bhi(ua[0]);  h[2] = blo(ua[1]);  h[3] = bhi(ua[1]);
  h[4] = blo(ua[2]);  h[5] = bhi(ua[2]);  h[6] = blo(ua[3]);  h[7] = bhi(ua[3]);
  h[8] = blo(ub[0]);  h[9] = bhi(ub[0]);  h[10] = blo(ub[1]); h[11] = bhi(ub[1]);
  h[12] = blo(ub[2]); h[13] = bhi(ub[2]); h[14] = blo(ub[3]); h[15] = bhi(ub[3]);
  float v = s[gw] * b2s[lane];
#pragma unroll
  for (int j = 0; j < 16; j++) v = fmaf(h[j], W2s[(j << 6) + lane], v);
  float m = v;
#pragma unroll
  for (int off = 32; off; off >>= 1) m = fmaxf(m, __shfl_xor(m, off, 64));
  float e = __expf(v - m);
  float ssum = e;
#pragma unroll
  for (int off = 32; off; off >>= 1) ssum += __shfl_xor(ssum, off, 64);
  const float r = v - m - __logf(ssum);
  const size_t o = (((size_t)gw) << 6) + lane;
  if (f0) ((__hip_bfloat16*)out)[o] = __float2bfloat16(r);
  else ((float*)out)[o] = r;
}

extern "C" void kernel_launch(void* const* d_in, const int* in_sizes, int n_in,
                              void* d_out, int out_size, void* d_ws, size_t ws_size,
                              hipStream_t stream) {
  (void)n_in; (void)out_size; (void)ws_size;
  const void* x  = d_in[0];
  const void* W1 = d_in[1];
  const void* b1 = d_in[2];
  const void* W2 = d_in[3];
  const void* b2 = d_in[4];
  const int* ei  = (const int*)d_in[5];

  const int N = in_sizes[0] / 512;
  const int E = in_sizes[5] / 2;
  const int NB = (N + BN - 1) >> BSH;      // 782 for N=100k (fits NBMAX=800)

  char* w = (char*)d_ws;
  size_t off = 0;
  auto alloc = [&](size_t bytes) -> void* {
    void* p = w + off;
    off += (bytes + 255) & ~(size_t)255;
    return p;
  };
  // Region A: bpair bucket regions (build) overlaid by the propagation
  // buffers (h10, pha, phb: [N][16] bf16; sa, sb: [N] f32).
  const size_t h16b = (size_t)N * 16 * 2;       // 3.2MB
  const size_t sb_  = ((size_t)N * 4 + 255) & ~(size_t)255;
  const size_t propb = 3 * ((h16b + 255) & ~(size_t)255) + 2 * sb_;
  const size_t bpb = (size_t)NB * CAP * 8;
  char*  regionA = (char*)alloc(propb > bpb ? propb : bpb);
  const size_t h16a = (h16b + 255) & ~(size_t)255;
  u16*   h10 = (u16*)regionA;
  u16*   pha = (u16*)(regionA + h16a);
  u16*   phb = (u16*)(regionA + 2 * h16a);
  float* sa  = (float*)(regionA + 3 * h16a);
  float* sb  = (float*)(regionA + 3 * h16a + sb_);
  uint2* bpair  = (uint2*)regionA;
  uint2* epk2   = (uint2*)alloc((size_t)E * 8);       // compact, lives on
  float* dinv   = (float*)alloc((size_t)N * 4);
  int*   gcur   = (int*)alloc((size_t)NB * 4);
  int*   cbase  = (int*)alloc(((size_t)NB + 1) * 4);
  int*   flags  = (int*)alloc(256);

  hipMemsetAsync(gcur, 0, (size_t)NB * 4, stream);
  detect_k<<<1, 1024, 0, stream>>>(x, ei, flags);
  scat_k<<<SCWG, 256, 0, stream>>>(ei, E, N, NB, gcur, bpair, flags);
  bscan_k<<<1, 64, 0, stream>>>(gcur, NB, cbase);
  deg_k<<<NB, 256, 0, stream>>>(bpair, gcur, dinv, N, NB);
  pack_k<<<NB, 256, 0, stream>>>(bpair, gcur, cbase, dinv, epk2, N, NB);
  // mlp after pack: prop buffers overwrite bpair (lifetime ended).
  mlp_k<<<(N + 63) / 64, 256, 0, stream>>>(x, W1, b1, flags, h10, pha, sa, N);

  for (int it = 0; it < 10; ++it) {
    if ((it & 1) == 0)
      gatherB_k<<<NB, 256, 0, stream>>>(pha, sa, h10, epk2, cbase, gcur,
                                        dinv, phb, sb, N, NB);
    else
      gatherB_k<<<NB, 256, 0, stream>>>(phb, sb, h10, epk2, cbase, gcur,
                                        dinv, pha, sa, N, NB);
  }
  // it9 (odd) wrote pha/sa
  const int gblocks = (N + WPB - 1) / WPB;
  out_k<<<gblocks, 256, 0, stream>>>(pha, sa, W2, b2, d_out, flags, N);
}

// Round 8
// 1029.968 us; speedup vs baseline: 3.9945x; 3.9945x over previous
//
#include <hip/hip_runtime.h>
#include <hip/hip_bf16.h>
#include <hip/hip_fp16.h>

// APPNP: h0 = MLP(x); 10x { h = 0.9 * A_hat h + 0.1 * h0 }; log_softmax.
// A_hat = D^-1/2 (A + I) D^-1/2 over col-targets (PyG gcn_norm).
//
// R10 post-mortem: edge-parallel gather invariant at ~362us across all
// configs -> dead branch. Node-per-wave ladder: R0 (128B rows) 84us/iter ==
// R8 (32B rows + 4B s + 4B edge) 85us/iter -> cost ~ scattered REQUESTS per
// edge (R0: 2, R8: 2.1 — the s load ate the row savings), not bytes.
// R11: one 64B line per edge. Augmented rows [N][32]u16 = 16 bf16 H +
// f32 s + pad, 64B-aligned; s obeys the same recurrence (h10 s-slot = 1.0).
// Quad of 4 lanes reads H+s from ONE line -> ~1.06 req/edge. nt only on the
// read-once epk stream; parallel bscan (serial one was ~20us).
// (R7 bench was an infra failure — container acquisition; identical resubmit.)

typedef unsigned short u16;
typedef __attribute__((ext_vector_type(8))) short short8;
typedef __attribute__((ext_vector_type(4))) float f32x4;
typedef __attribute__((ext_vector_type(4))) unsigned u32x4;

#define WPB 4        // waves per 256-thread block (gather/out)
#define BSH2 9       // 512 nodes per bucket
#define BN2 512
#define NBMAX 200
#define CAP 20480    // slots per bucket region (mean 16.3k, +32 sigma)
#define SCWG 392     // scatter WGs (chunk ~8.2k edges)

// ---- helpers -------------------------------------------------------------
__device__ __forceinline__ float loadF(const void* p, size_t i, int bf) {
  if (bf) return __bfloat162float(((const __hip_bfloat16*)p)[i]);
  return ((const float*)p)[i];
}
__device__ __forceinline__ float blo(unsigned u) {
  return __uint_as_float(u << 16);
}
__device__ __forceinline__ float bhi(unsigned u) {
  return __uint_as_float(u & 0xffff0000u);
}
__device__ __forceinline__ u16 f2b(float v) {
  __hip_bfloat16 b = __float2bfloat16(v);
  return *reinterpret_cast<u16*>(&b);
}
__device__ __forceinline__ unsigned pk2(float lo, float hi) {
  return (unsigned)f2b(lo) | ((unsigned)f2b(hi) << 16);
}
__device__ __forceinline__ int clampN(int v, int N) {
  v = v < 0 ? 0 : v;
  return v >= N ? N - 1 : v;
}
__device__ __forceinline__ float nrm_of(unsigned e) {
  return __half2float(__ushort_as_half((unsigned short)(e & 0x7fffu)));
}

// flags[0]: 1 if float tensors bf16; flags[1]: 1 if edge_index int64.
__global__ void detect_k(const void* x, const int* ei, int* flags) {
  __shared__ int red[2];
  const int tid = threadIdx.x;              // 1024 threads
  if (tid < 2) red[tid] = 0;
  __syncthreads();
  const __hip_bfloat16* xb = (const __hip_bfloat16*)x;
  float v = __bfloat162float(xb[tid]);
  int sane = (v == v && fabsf(v) < 64.f) ? 1 : 0;
  int zer = (ei[2 * tid + 1] == 0) ? 1 : 0;
  atomicAdd(&red[0], sane);
  atomicAdd(&red[1], zer);
  __syncthreads();
  if (tid == 0) {
    flags[0] = (red[0] >= 1024 - 32) ? 1 : 0;
    flags[1] = (red[1] >= 1024 - 128) ? 1 : 0;
  }
}

// Two-pass chunked scatter: per WG, (A) LDS-histogram chunk over buckets,
// (B) reserve one contiguous range per bucket, (C) re-read chunk and write
// (src,dst) into the WG-owned run -> full-line writes from one CU.
__global__ __launch_bounds__(256) void scat_k(
    const int* __restrict__ ei, int E, int N, int NB,
    int* __restrict__ gcur, uint2* __restrict__ bpair,
    const int* __restrict__ flags) {
  __shared__ int hist[NBMAX];
  __shared__ int resv[NBMAX];
  const int tid = threadIdx.x;
  const int chunk = (E + SCWG - 1) / SCWG;
  const int e0 = blockIdx.x * chunk;
  const int e1 = min(e0 + chunk, E);
  if (e0 >= E) return;
  const int wide = flags[1];
  for (int i = tid; i < NB; i += 256) hist[i] = 0;
  __syncthreads();
  for (int e = e0 + tid; e < e1; e += 256) {
    int c = wide ? ei[2 * ((long)E + e)] : ei[(long)E + e];
    atomicAdd(&hist[clampN(c, N) >> BSH2], 1);
  }
  __syncthreads();
  for (int b = tid; b < NB; b += 256) {
    int cnt = hist[b];
    resv[b] = cnt ? atomicAdd(&gcur[b], cnt) : 0;
  }
  __syncthreads();
  for (int i = tid; i < NB; i += 256) hist[i] = 0;
  __syncthreads();
  for (int e = e0 + tid; e < e1; e += 256) {
    int r = wide ? ei[2 * (long)e] : ei[e];
    int c = wide ? ei[2 * ((long)E + e)] : ei[(long)E + e];
    r = clampN(r, N); c = clampN(c, N);
    const int b = c >> BSH2;
    const int pos = resv[b] + atomicAdd(&hist[b], 1);
    if (pos < CAP)
      bpair[(size_t)b * CAP + pos] = make_uint2((unsigned)r, (unsigned)c);
  }
}

// Parallel scan over bucket totals (NB <= 256) -> CSR bucket bases.
__global__ __launch_bounds__(256) void bscan_k(const int* __restrict__ gcur,
                                               int NB, int* __restrict__ cbase) {
  __shared__ int v[256];
  const int tid = threadIdx.x;
  const int x = (tid < NB) ? min(gcur[tid], CAP) : 0;
  v[tid] = x;
  __syncthreads();
  for (int off = 1; off < 256; off <<= 1) {
    int t = (tid >= off) ? v[tid - off] : 0;
    __syncthreads();
    v[tid] += t;
    __syncthreads();
  }
  if (tid < NB) cbase[tid] = v[tid] - x;       // exclusive
  if (tid == NB - 1) cbase[NB] = v[tid];
}

// Per bucket: LDS histogram over its 512 nodes + LDS scan -> colptr, dinv.
__global__ __launch_bounds__(1024) void fill2a_k(
    const uint2* __restrict__ bpair, const int* __restrict__ gcur,
    const int* __restrict__ cbase, int* __restrict__ colptr,
    float* __restrict__ dinv, int N, int NB) {
  __shared__ int lhist[BN2];
  __shared__ int pref[BN2];
  const int b = blockIdx.x;
  const int tid = threadIdx.x;
  const int nb0 = b << BSH2;
  const int nn = min(BN2, N - nb0);
  if (tid < BN2) lhist[tid] = 0;
  __syncthreads();
  const size_t wbeg = (size_t)b * CAP;
  const int cnt = min(gcur[b], CAP);
  for (int i = tid; i < cnt; i += 1024) {
    int dl = (int)bpair[wbeg + i].y - nb0;
    atomicAdd(&lhist[dl], 1);
  }
  __syncthreads();
  if (tid < BN2) pref[tid] = lhist[tid];
  __syncthreads();
  for (int off = 1; off < BN2; off <<= 1) {
    int v = 0;
    if (tid < BN2 && tid >= off) v = pref[tid - off];
    __syncthreads();
    if (tid < BN2) pref[tid] += v;
    __syncthreads();
  }
  if (tid < nn) {
    const int excl = pref[tid] - lhist[tid];
    colptr[nb0 + tid] = cbase[b] + excl;
    dinv[nb0 + tid] = rsqrtf(1.0f + (float)lhist[tid]);
  }
  if (b == NB - 1 && tid == 0) colptr[N] = cbase[NB];
}

// Per bucket: scatter edges to exact CSR slots, packing src<<15 | fp16(norm).
// norm = dinv[src]*dinv[dst] in (0,1] -> fp16-normal, sign 0 (15 bits);
// src < 131072 fits 17 bits.
__global__ __launch_bounds__(1024) void fill2b_k(
    const uint2* __restrict__ bpair, const int* __restrict__ gcur,
    const int* __restrict__ colptr, const float* __restrict__ dinv,
    unsigned* __restrict__ epk, int N, int NB) {
  __shared__ int lcur[BN2];
  __shared__ float ldv[BN2];
  const int b = blockIdx.x;
  const int tid = threadIdx.x;
  const int nb0 = b << BSH2;
  const int nn = min(BN2, N - nb0);
  if (tid < nn) {
    lcur[tid] = colptr[nb0 + tid];
    ldv[tid] = dinv[nb0 + tid];
  }
  __syncthreads();
  const size_t wbeg = (size_t)b * CAP;
  const int cnt = min(gcur[b], CAP);
  for (int i = tid; i < cnt; i += 1024) {
    const uint2 p = bpair[wbeg + i];
    const int dl = (int)p.y - nb0;
    const int slot = atomicAdd(&lcur[dl], 1);
    const float nrm = dinv[p.x] * ldv[dl];
    epk[slot] = (p.x << 15) | (unsigned)__half_as_ushort(__float2half(nrm));
  }
}

// MLP stage 1: H1 = relu(x@W1 + b1) -> augmented 64B rows [N][32]u16:
// u16[0..15] = H bf16, u16[16..17] = s f32 (init 1.0), rest pad.
__global__ __launch_bounds__(256) void mlp_k(
    const void* __restrict__ x, const void* __restrict__ W1,
    const void* __restrict__ b1, const int* __restrict__ flags,
    u16* __restrict__ h10, u16* __restrict__ pha, int N) {
  __shared__ __align__(16) short Blds[8192];   // [kstep][lane][j] bf16
  __shared__ float b1s[16];
  __shared__ float h1s[WPB][16][17];

  const int tid = threadIdx.x;
  const int f0 = flags[0];

  for (int idx = tid; idx < 8192; idx += 256) {
    int ks = idx >> 9, ln = (idx >> 3) & 63, j = idx & 7;
    int k = ks * 32 + ((ln >> 4) << 3) + j;
    int n = ln & 15;
    float w = loadF(W1, (size_t)k * 16 + n, f0);
    Blds[idx] = (short)f2b(w);
  }
  if (tid < 16) b1s[tid] = loadF(b1, tid, f0);
  __syncthreads();

  const int lane = tid & 63;
  const int wv = tid >> 6;
  const int tile = (blockIdx.x * WPB + wv) * 16;
  if (tile >= N) return;

  const int m = lane & 15;
  const int quad = lane >> 4;
  const int row = min(tile + m, N - 1);
  const size_t rowbase = (size_t)row * 512 + (quad << 3);

  f32x4 acc = {0.f, 0.f, 0.f, 0.f};
  if (f0) {
    short8 af[16];
#pragma unroll
    for (int ks = 0; ks < 16; ks++)
      af[ks] = *reinterpret_cast<const short8*>((const u16*)x + rowbase + ks * 32);
#pragma unroll
    for (int ks = 0; ks < 16; ks++) {
      const short8 bf = *reinterpret_cast<const short8*>(&Blds[(ks * 64 + lane) * 8]);
      acc = __builtin_amdgcn_mfma_f32_16x16x32_bf16(af[ks], bf, acc, 0, 0, 0);
    }
  } else {
#pragma unroll
    for (int ks = 0; ks < 16; ks++) {
      short8 a;
      const float* xf = (const float*)x + rowbase + ks * 32;
      const float4 lo = *reinterpret_cast<const float4*>(xf);
      const float4 hi = *reinterpret_cast<const float4*>(xf + 4);
      a[0] = (short)f2b(lo.x); a[1] = (short)f2b(lo.y);
      a[2] = (short)f2b(lo.z); a[3] = (short)f2b(lo.w);
      a[4] = (short)f2b(hi.x); a[5] = (short)f2b(hi.y);
      a[6] = (short)f2b(hi.z); a[7] = (short)f2b(hi.w);
      const short8 bf = *reinterpret_cast<const short8*>(&Blds[(ks * 64 + lane) * 8]);
      acc = __builtin_amdgcn_mfma_f32_16x16x32_bf16(a, bf, acc, 0, 0, 0);
    }
  }

#pragma unroll
  for (int r = 0; r < 4; r++)
    h1s[wv][quad * 4 + r][m] = fmaxf(acc[r] + b1s[m], 0.f);
  // same-wave LDS write->read; compiler inserts lgkmcnt wait, no barrier.

  const int node = lane >> 2;                 // 0..15
  const int gnode = tile + node;
  if (gnode < N) {
    const int cp = (lane & 3) << 2;           // channel offset 0,4,8,12
    uint2 pv;
    pv.x = pk2(h1s[wv][node][cp + 0], h1s[wv][node][cp + 1]);
    pv.y = pk2(h1s[wv][node][cp + 2], h1s[wv][node][cp + 3]);
    const size_t rb = ((size_t)gnode) << 5;
    *reinterpret_cast<uint2*>(h10 + rb + cp) = pv;
    *reinterpret_cast<uint2*>(pha + rb + cp) = pv;
    if ((lane & 3) == 0) {
      *reinterpret_cast<float*>(h10 + rb + 16) = 1.0f;
      *reinterpret_cast<float*>(pha + rb + 16) = 1.0f;
    }
  }
}

// Node-per-wave gather over augmented 64B rows. Wave = 16 edge-slots x
// 4 lanes; quad reads H (4x8B) + s (4B) from ONE 64B line -> ~1 scattered
// request per edge. Unroll 2, two acc banks; nt only on epk.
__global__ __launch_bounds__(256) void gather_k(
    const u16* __restrict__ hcur, const u16* __restrict__ h10,
    const int* __restrict__ colptr, const unsigned* __restrict__ epk,
    const float* __restrict__ dinv, u16* __restrict__ hnext, int N) {
  const int gw = (int)((blockIdx.x * 256u + threadIdx.x) >> 6);
  if (gw >= N) return;
  const int lane = threadIdx.x & 63;
  const int es = lane >> 2;                   // edge slot 0..15
  const int q = lane & 3;                     // channel quarter
  const int co = q << 2;                      // u16 offset (4 ch)
  const int beg = __builtin_amdgcn_readfirstlane(colptr[gw]);
  const int end = __builtin_amdgcn_readfirstlane(colptr[gw + 1]);

  float a0 = 0.f, a1 = 0.f, a2 = 0.f, a3 = 0.f, as = 0.f;
  float c0 = 0.f, c1 = 0.f, c2 = 0.f, c3 = 0.f, cs = 0.f;
  int t = beg + es;
  for (; t + 16 < end; t += 32) {
    const unsigned e0 = __builtin_nontemporal_load(epk + t);
    const unsigned e1 = __builtin_nontemporal_load(epk + t + 16);
    const u16* r0 = hcur + (((size_t)(e0 >> 15)) << 5);
    const u16* r1 = hcur + (((size_t)(e1 >> 15)) << 5);
    const uint2 u0 = *reinterpret_cast<const uint2*>(r0 + co);
    const uint2 u1 = *reinterpret_cast<const uint2*>(r1 + co);
    const float sv0 = *reinterpret_cast<const float*>(r0 + 16);
    const float sv1 = *reinterpret_cast<const float*>(r1 + 16);
    const float n0 = nrm_of(e0), n1 = nrm_of(e1);
    a0 = fmaf(n0, blo(u0.x), a0); a1 = fmaf(n0, bhi(u0.x), a1);
    a2 = fmaf(n0, blo(u0.y), a2); a3 = fmaf(n0, bhi(u0.y), a3);
    as = fmaf(n0, sv0, as);
    c0 = fmaf(n1, blo(u1.x), c0); c1 = fmaf(n1, bhi(u1.x), c1);
    c2 = fmaf(n1, blo(u1.y), c2); c3 = fmaf(n1, bhi(u1.y), c3);
    cs = fmaf(n1, sv1, cs);
  }
  if (t < end) {
    const unsigned e0 = __builtin_nontemporal_load(epk + t);
    const u16* r0 = hcur + (((size_t)(e0 >> 15)) << 5);
    const uint2 u0 = *reinterpret_cast<const uint2*>(r0 + co);
    const float sv0 = *reinterpret_cast<const float*>(r0 + 16);
    const float n0 = nrm_of(e0);
    a0 = fmaf(n0, blo(u0.x), a0); a1 = fmaf(n0, bhi(u0.x), a1);
    a2 = fmaf(n0, blo(u0.y), a2); a3 = fmaf(n0, bhi(u0.y), a3);
    as = fmaf(n0, sv0, as);
  }
  a0 += c0; a1 += c1; a2 += c2; a3 += c3; as += cs;
  // reduce across 16 edge slots (lane bits 2..5); q preserved
#pragma unroll
  for (int d = 4; d <= 32; d <<= 1) {
    a0 += __shfl_xor(a0, d, 64); a1 += __shfl_xor(a1, d, 64);
    a2 += __shfl_xor(a2, d, 64); a3 += __shfl_xor(a3, d, 64);
    as += __shfl_xor(as, d, 64);
  }
  if (es == 0) {
    const size_t rb = ((size_t)gw) << 5;
    const uint2 hs = *reinterpret_cast<const uint2*>(hcur + rb + co);
    const uint2 hz = *reinterpret_cast<const uint2*>(h10 + rb + co);
    const float ss = *reinterpret_cast<const float*>(hcur + rb + 16);
    const float sz = *reinterpret_cast<const float*>(h10 + rb + 16);
    const float di = dinv[gw];
    const float dd = di * di;
    const float r0 = 0.9f * (a0 + dd * blo(hs.x)) + 0.1f * blo(hz.x);
    const float r1 = 0.9f * (a1 + dd * bhi(hs.x)) + 0.1f * bhi(hz.x);
    const float r2 = 0.9f * (a2 + dd * blo(hs.y)) + 0.1f * blo(hz.y);
    const float r3 = 0.9f * (a3 + dd * bhi(hs.y)) + 0.1f * bhi(hz.y);
    uint2 pv;
    pv.x = pk2(r0, r1); pv.y = pk2(r2, r3);
    *reinterpret_cast<uint2*>(hnext + rb + co) = pv;
    if (q == 0)
      *reinterpret_cast<float*>(hnext + rb + 16) =
          0.9f * (as + dd * ss) + 0.1f * sz;
  }
}

// Final: out = log_softmax(H @ W2 + s * b2), one wave per node, f32 math.
__global__ __launch_bounds__(256) void out_k(
    const u16* __restrict__ ph1, const void* __restrict__ W2,
    const void* __restrict__ b2, void* __restrict__ out,
    const int* __restrict__ flags, int N) {
  __shared__ float W2s[16 * 64];
  __shared__ float b2s[64];
  const int tid = threadIdx.x;
  const int f0 = flags[0];
  for (int i = tid; i < 1024; i += 256) W2s[i] = loadF(W2, i, f0);
  if (tid < 64) b2s[tid] = loadF(b2, tid, f0);
  __syncthreads();
  const int gw = (int)((blockIdx.x * 256u + tid) >> 6);
  if (gw >= N) return;
  const int lane = tid & 63;
  const u16* row = ph1 + (((size_t)gw) << 5);
  const u32x4 ua = *reinterpret_cast<const u32x4*>(row);       // ch 0..7
  const u32x4 ub = *reinterpret_cast<const u32x4*>(row + 8);   // ch 8..15
  const float s = *reinterpret_cast<const float*>(row + 16);
  float h[16];
  h[0] = blo(ua[0]);  h[1] = bhi(ua[0]);  h[2] = blo(ua[1]);  h[3] = bhi(ua[1]);
  h[4] = blo(ua[2]);  h[5] = bhi(ua[2]);  h[6] = blo(ua[3]);  h[7] = bhi(ua[3]);
  h[8] = blo(ub[0]);  h[9] = bhi(ub[0]);  h[10] = blo(ub[1]); h[11] = bhi(ub[1]);
  h[12] = blo(ub[2]); h[13] = bhi(ub[2]); h[14] = blo(ub[3]); h[15] = bhi(ub[3]);
  float v = s * b2s[lane];
#pragma unroll
  for (int j = 0; j < 16; j++) v = fmaf(h[j], W2s[(j << 6) + lane], v);
  float m = v;
#pragma unroll
  for (int off = 32; off; off >>= 1) m = fmaxf(m, __shfl_xor(m, off, 64));
  float e = __expf(v - m);
  float ssum = e;
#pragma unroll
  for (int off = 32; off; off >>= 1) ssum += __shfl_xor(ssum, off, 64);
  const float r = v - m - __logf(ssum);
  const size_t o = (((size_t)gw) << 6) + lane;
  if (f0) ((__hip_bfloat16*)out)[o] = __float2bfloat16(r);
  else ((float*)out)[o] = r;
}

extern "C" void kernel_launch(void* const* d_in, const int* in_sizes, int n_in,
                              void* d_out, int out_size, void* d_ws, size_t ws_size,
                              hipStream_t stream) {
  (void)n_in; (void)out_size; (void)ws_size;
  const void* x  = d_in[0];
  const void* W1 = d_in[1];
  const void* b1 = d_in[2];
  const void* W2 = d_in[3];
  const void* b2 = d_in[4];
  const int* ei  = (const int*)d_in[5];

  const int N = in_sizes[0] / 512;
  const int E = in_sizes[5] / 2;
  const int NB = (N + BN2 - 1) >> BSH2;    // 196 for N=100k (fits NBMAX=200)

  char* w = (char*)d_ws;
  size_t off = 0;
  auto alloc = [&](size_t bytes) -> void* {
    void* p = w + off;
    off += (bytes + 255) & ~(size_t)255;
    return p;
  };
  // Region A: bpair bucket regions (build) overlaid by the propagation
  // buffers (h10, pha, phb: [N][32] u16 = 64B rows).
  const size_t hrow = ((size_t)N * 64 + 255) & ~(size_t)255;   // 6.4MB
  const size_t propb = 3 * hrow;
  const size_t bpb = (size_t)NB * CAP * 8;
  char*  regionA = (char*)alloc(propb > bpb ? propb : bpb);
  u16*   h10 = (u16*)regionA;
  u16*   pha = (u16*)(regionA + hrow);
  u16*   phb = (u16*)(regionA + 2 * hrow);
  uint2* bpair  = (uint2*)regionA;
  unsigned* epk = (unsigned*)alloc((size_t)E * 4);
  int*   colptr = (int*)alloc(((size_t)N + 1) * 4);
  float* dinv   = (float*)alloc((size_t)N * 4);
  int*   gcur   = (int*)alloc((size_t)NB * 4);
  int*   cbase  = (int*)alloc(((size_t)NB + 1) * 4);
  int*   flags  = (int*)alloc(256);

  hipMemsetAsync(gcur, 0, (size_t)NB * 4, stream);
  detect_k<<<1, 1024, 0, stream>>>(x, ei, flags);
  scat_k<<<SCWG, 256, 0, stream>>>(ei, E, N, NB, gcur, bpair, flags);
  bscan_k<<<1, 256, 0, stream>>>(gcur, NB, cbase);
  fill2a_k<<<NB, 1024, 0, stream>>>(bpair, gcur, cbase, colptr, dinv, N, NB);
  fill2b_k<<<NB, 1024, 0, stream>>>(bpair, gcur, colptr, dinv, epk, N, NB);
  // mlp after fill2b: prop buffers overwrite bpair (lifetime ended).
  mlp_k<<<(N + 63) / 64, 256, 0, stream>>>(x, W1, b1, flags, h10, pha, N);

  const int gblocks = (N + WPB - 1) / WPB;
  for (int it = 0; it < 10; ++it) {
    if ((it & 1) == 0)
      gather_k<<<gblocks, 256, 0, stream>>>(pha, h10, colptr, epk, dinv, phb, N);
    else
      gather_k<<<gblocks, 256, 0, stream>>>(phb, h10, colptr, epk, dinv, pha, N);
  }
  // it9 (odd) wrote pha
  out_k<<<gblocks, 256, 0, stream>>>(pha, W2, b2, d_out, flags, N);
}